// Round 5
// baseline (133.403 us; speedup 1.0000x reference)
//
#include <hip/hip_runtime.h>
#include <hip/hip_bf16.h>

#define S 1024
#define H 16
#define BS 2
#define D 1024
#define CH 8   // rows per k12 chunk

typedef float f32x4 __attribute__((ext_vector_type(4)));

// ============ Kernel 1 (fused): M/u prep + LN stats + scores -> p_up/p_dn ============
// grid: (128 chunks, 2 b), block 256. Each block: 8 output rows x all 16 heads.
__global__ __launch_bounds__(256) void k12(const float* __restrict__ ctx,
                                           const float* __restrict__ lnw,
                                           const float* __restrict__ lnb,
                                           const float* __restrict__ wk,
                                           const float* __restrict__ wq,
                                           const float* __restrict__ bq,
                                           float* __restrict__ p_up,
                                           float* __restrict__ p_dn) {
    __shared__ float Ml[64 * 65];        // M[a][e] at Ml[e*65+a]
    __shared__ float uw[64];
    __shared__ float xs[CH + 2][1032];   // ctx slab rows r0-1..r0+CH, then normalized
    __shared__ float ts[CH + 2][68];     // per-head t = M x
    __shared__ float mu[CH + 2], rs[CH + 2];
    __shared__ float lw[1024], lb[1024];

    int t = threadIdx.x;
    int lane = t & 63, w = t >> 6;
    int chunk = blockIdx.x, b = blockIdx.y;
    int r0 = chunk * CH;

    // ---- Phase A: stage Wq,Wk into xs region (alias), compute M and u ----
    float* WqL = &xs[0][0];          // [64][65]
    float* WkL = &xs[0][0] + 4160;   // [64][65]
    for (int idx = t; idx < 4096; idx += 256) {
        int d = idx >> 6, c = idx & 63;
        WqL[d * 65 + c] = wq[idx];
        WkL[d * 65 + c] = wk[idx];
    }
    // lnw/lnb -> LDS (independent region)
    ((f32x4*)lw)[t] = ((const f32x4*)lnw)[t];
    ((f32x4*)lb)[t] = ((const f32x4*)lnb)[t];
    __syncthreads();
    for (int ee = 0; ee < 16; ++ee) {
        int e = w * 16 + ee;
        float acc = 0.0f;
        #pragma unroll 8
        for (int d = 0; d < 64; ++d) acc += WqL[d * 65 + lane] * WkL[d * 65 + e];
        Ml[e * 65 + lane] = acc;
    }
    if (w == 0) {
        float acc = 0.0f;
        #pragma unroll 8
        for (int d = 0; d < 64; ++d) acc += bq[d] * WkL[d * 65 + lane];
        uw[lane] = acc;
    }
    __syncthreads();

    // ---- Phase B: stage ctx slab (rows r0-1 .. r0+CH), f32x4 per thread per row ----
    #pragma unroll
    for (int q = 0; q < CH + 2; ++q) {
        int gr = r0 - 1 + q;
        f32x4 v = {0.f, 0.f, 0.f, 0.f};
        if (gr >= 0 && gr < S) v = ((const f32x4*)(ctx + ((size_t)b * S + gr) * D))[t];
        *(f32x4*)&xs[q][t * 4] = v;
    }
    // M column 'lane' -> registers (head-independent), conflict-free LDS reads
    float Mreg[64];
    #pragma unroll
    for (int e = 0; e < 64; ++e) Mreg[e] = Ml[e * 65 + lane];
    __syncthreads();

    // ---- Phase C: LN stats per row ----
    for (int q = w; q < CH + 2; q += 4) {
        float s = 0.f, sq = 0.f;
        #pragma unroll
        for (int k = 0; k < 4; ++k) {
            f32x4 v = *(const f32x4*)&xs[q][(lane + 64 * k) * 4];
            s += v.x + v.y + v.z + v.w;
            sq += v.x * v.x + v.y * v.y + v.z * v.z + v.w * v.w;
        }
        #pragma unroll
        for (int off = 32; off > 0; off >>= 1) {
            s += __shfl_down(s, off);
            sq += __shfl_down(sq, off);
        }
        if (lane == 0) {
            float m = s * (1.0f / D);
            float var = sq * (1.0f / D) - m * m;
            mu[q] = m;
            rs[q] = rsqrtf(var + 1e-5f);
        }
    }
    __syncthreads();

    // ---- Phase D: normalize in place ----
    #pragma unroll
    for (int q = 0; q < CH + 2; ++q) {
        float m = mu[q], r = rs[q];
        f32x4 v = *(const f32x4*)&xs[q][t * 4];
        f32x4 wv = *(const f32x4*)&lw[t * 4];
        f32x4 bv = *(const f32x4*)&lb[t * 4];
        v.x = (v.x - m) * r * wv.x + bv.x;
        v.y = (v.y - m) * r * wv.y + bv.y;
        v.z = (v.z - m) * r * wv.z + bv.z;
        v.w = (v.w - m) * r * wv.w + bv.w;
        *(f32x4*)&xs[q][t * 4] = v;
    }
    __syncthreads();

    // ---- Phase E: per head: matvec + score diff + sigmoid ----
    for (int h = 0; h < H; ++h) {
        int hc = h * 64;
        for (int q = w; q < CH + 2; q += 4) {
            float a0 = 0.f, a1 = 0.f, a2 = 0.f, a3 = 0.f;
            #pragma unroll
            for (int eq = 0; eq < 16; ++eq) {
                f32x4 xv = *(const f32x4*)&xs[q][hc + eq * 4];  // uniform broadcast
                a0 += Mreg[eq * 4 + 0] * xv.x;
                a1 += Mreg[eq * 4 + 1] * xv.y;
                a2 += Mreg[eq * 4 + 2] * xv.z;
                a3 += Mreg[eq * 4 + 3] * xv.w;
            }
            ts[q][lane] = (a0 + a1) + (a2 + a3);
        }
        __syncthreads();
        for (int lr = 1 + w; lr <= CH; lr += 4) {
            int i = r0 + lr - 1;
            float xi = xs[lr][hc + lane];
            float tp = ts[lr + 1][lane] - ts[lr - 1][lane];
            float xd = xs[lr + 1][hc + lane] - xs[lr - 1][hc + lane];
            float v = xi * tp + uw[lane] * xd;
            #pragma unroll
            for (int off = 32; off > 0; off >>= 1) v += __shfl_down(v, off);
            if (lane == 0) {
                float z = v * (1.0f / 64.0f);
                float pu, pd;
                if (i == 0)          { pu = 1.0f; pd = 0.0f; }
                else if (i == S - 1) { pu = 0.0f; pd = 1.0f; }
                else {
                    float ez = __expf(-z);
                    pu = 1.0f / (1.0f + ez);
                    pd = 1.0f - pu;
                }
                int bh = b * H + h;
                p_up[bh * S + i] = pu;
                p_dn[bh * S + i] = pd;
            }
        }
        __syncthreads();
    }
}

// ---------------- Kernel 2: n_up, blend superdiag with prior, log, shfl scan -> C ----
__global__ __launch_bounds__(1024) void k_scan(const float* __restrict__ p_up,
                                               const float* __restrict__ p_dn,
                                               const float* __restrict__ prior,
                                               float* __restrict__ n_up,
                                               float* __restrict__ C) {
    int bh = blockIdx.x;
    int t = threadIdx.x;
    float L = 0.0f;
    if (t > 0) {
        int i = t - 1;  // 0..1022
        float nr = sqrtf(p_up[bh * S + i] * p_dn[bh * S + i + 1] + 1e-4f);
        n_up[bh * S + i] = nr;
        float pr = prior[((size_t)bh * S + i) * S + i + 1];
        float N = pr + (1.0f - pr) * nr;
        L = logf(N + 1e-9f);
    }
    int lane = t & 63, wid = t >> 6;
    float val = L;
    #pragma unroll
    for (int off = 1; off < 64; off <<= 1) {
        float v = __shfl_up(val, off, 64);
        if (lane >= off) val += v;
    }
    __shared__ float wsum[16];
    if (lane == 63) wsum[wid] = val;
    __syncthreads();
    if (t < 16) {
        float v2 = wsum[t];
        #pragma unroll
        for (int off = 1; off < 16; off <<= 1) {
            float x = __shfl_up(v2, off, 64);
            if (t >= off) v2 += x;
        }
        wsum[t] = v2;
    }
    __syncthreads();
    float base = (wid > 0) ? wsum[wid - 1] : 0.0f;
    C[bh * S + t] = base + val;  // exclusive prefix over logn
}

// ---------------- Kernel 3: big elementwise pass -> g and neibor --------------------
// grid: 4096 blocks, each handles 8 consecutive rows of one bh; thread = 4 cols.
__global__ __launch_bounds__(256) void k_out(const float* __restrict__ prior,
                                             const float* __restrict__ n_up,
                                             const float* __restrict__ C,
                                             float* __restrict__ g_out,
                                             float* __restrict__ nb_out) {
    int t = threadIdx.x;
    int bid = blockIdx.x;          // 0..4095
    int bh = bid >> 7;
    int i0 = (bid & 127) * 8;
    int j0 = t * 4;
    const float* Crow = C + bh * S;
    f32x4 c4 = *(const f32x4*)(Crow + j0);          // this thread's C[j] quad (L2)
    f32x4 ciA = *(const f32x4*)(Crow + i0);         // C[i] for the block's 8 rows
    f32x4 ciB = *(const f32x4*)(Crow + i0 + 4);
    #pragma unroll
    for (int r = 0; r < 8; ++r) {
        int i = i0 + r;
        float Ci = (r < 4) ? ciA[r] : ciB[r - 4];
        size_t rowbase = ((size_t)bh * S + i) * S;
        f32x4 p4 = __builtin_nontemporal_load((const f32x4*)(prior + rowbase + j0));
        f32x4 nb, gg;
        // fast path: C monotone non-increasing -> g = exp(-|C[j]-C[i]|)+1e-4 for j!=i
        #pragma unroll
        for (int l = 0; l < 4; ++l) {
            nb[l] = fmaf(0.99f, p4[l], 0.01f);
            gg[l] = __expf(-fabsf(c4[l] - Ci)) + 1e-4f;
        }
        // slow fixup only where [i-1,i+1] intersects [j0,j0+3] (~1 wave per row)
        if (i - 1 <= j0 + 3 && i + 1 >= j0) {
            float nup_i  = (i < S - 1) ? n_up[bh * S + i] : 0.0f;
            float nup_im = (i > 0)     ? n_up[bh * S + i - 1] : 0.0f;
            #pragma unroll
            for (int l = 0; l < 4; ++l) {
                int j = j0 + l;
                if (j == i + 1) nb[l] = p4[l] + (1.0f - p4[l]) * nup_i;
                if (j == i - 1) nb[l] = p4[l] + (1.0f - p4[l]) * nup_im;
                if (j == i)     gg[l] = nb[l];   // diag: g = neibor (generic 0.01 blend)
            }
        }
        __builtin_nontemporal_store(gg, (f32x4*)(g_out + rowbase + j0));
        __builtin_nontemporal_store(nb, (f32x4*)(nb_out + rowbase + j0));
    }
}

extern "C" void kernel_launch(void* const* d_in, const int* in_sizes, int n_in,
                              void* d_out, int out_size, void* d_ws, size_t ws_size,
                              hipStream_t stream) {
    const float* ctx   = (const float*)d_in[0];
    // d_in[1] = eos_mask (all true) -- unused
    const float* prior = (const float*)d_in[2];
    const float* lnw   = (const float*)d_in[3];
    const float* lnb   = (const float*)d_in[4];
    const float* wk    = (const float*)d_in[5];
    // d_in[6] = bk -- cancels in the score difference
    const float* wq    = (const float*)d_in[7];
    const float* bq    = (const float*)d_in[8];

    float* ws = (float*)d_ws;
    float* p_up = ws;                  // 32*1024
    float* p_dn = ws + 32768;          // 32*1024
    float* n_up = ws + 65536;          // 32*1024
    float* C    = ws + 98304;          // 32*1024

    float* g_out  = (float*)d_out;
    float* nb_out = (float*)d_out + (size_t)BS * H * S * S;

    k12<<<dim3(S / CH, BS), 256, 0, stream>>>(ctx, lnw, lnb, wk, wq, bq, p_up, p_dn);
    k_scan<<<BS * H, 1024, 0, stream>>>(p_up, p_dn, prior, n_up, C);
    k_out<<<BS * H * S / 8, 256, 0, stream>>>(prior, n_up, C, g_out, nb_out);
}

// Round 6
// 110.291 us; speedup vs baseline: 1.2096x; 1.2096x over previous
//
#include <hip/hip_runtime.h>
#include <hip/hip_bf16.h>

#define S 1024
#define H 16
#define BS 2
#define D 1024

typedef float f32x4 __attribute__((ext_vector_type(4)));

// ---------------- Kernel 1: LN stats (blocks 0..2047) + M/u prep (blocks 2048..2051) --
// M[a][e] = sum_d Wq[d][a]*Wk[d][e]  (stored transposed: Mt[e*64+a])
// u[e]    = sum_d bq[d]*Wk[d][e]
__global__ __launch_bounds__(256) void k_ln_prep(const float* __restrict__ ctx,
                                                 const float* __restrict__ wk,
                                                 const float* __restrict__ wq,
                                                 const float* __restrict__ bq,
                                                 float* __restrict__ mean,
                                                 float* __restrict__ rstd,
                                                 float* __restrict__ Mt,
                                                 float* __restrict__ uvec) {
    __shared__ float sh[2 * 64 * 65];  // prep: Wq | Wk (padded).  LN: first 8 floats.
    int t = threadIdx.x;
    int bid = blockIdx.x;

    if (bid >= BS * S) {
        // ---- prep path: 4 blocks, each handles 16 values of e ----
        int p = bid - BS * S;  // 0..3
        float* WqL = sh;            // [64][65]
        float* WkL = sh + 64 * 65;  // [64][65]
        for (int idx = t; idx < 4096; idx += 256) {
            int d = idx >> 6, c = idx & 63;
            WqL[d * 65 + c] = wq[idx];
            WkL[d * 65 + c] = wk[idx];
        }
        __syncthreads();
        int a = t & 63, sub = t >> 6;
        for (int ee = sub; ee < 16; ee += 4) {
            int e = p * 16 + ee;
            float acc = 0.0f;
            #pragma unroll 8
            for (int d = 0; d < 64; ++d) acc += WqL[d * 65 + a] * WkL[d * 65 + e];
            Mt[e * 64 + a] = acc;
        }
        if (p == 0 && t < 64) {
            float acc = 0.0f;
            #pragma unroll 8
            for (int d = 0; d < 64; ++d) acc += bq[d] * WkL[d * 65 + t];
            uvec[t] = acc;
        }
        return;
    }

    // ---- LN stats path ----
    const float* x = ctx + (size_t)bid * D;
    float4 v = *(const float4*)(x + t * 4);
    float s = v.x + v.y + v.z + v.w;
    float sq = v.x * v.x + v.y * v.y + v.z * v.z + v.w * v.w;
    #pragma unroll
    for (int off = 32; off > 0; off >>= 1) {
        s += __shfl_down(s, off);
        sq += __shfl_down(sq, off);
    }
    float* ss = sh;       // [4]
    float* sqs = sh + 4;  // [4]
    int w = t >> 6;
    if ((t & 63) == 0) { ss[w] = s; sqs[w] = sq; }
    __syncthreads();
    if (t == 0) {
        float sum = ss[0] + ss[1] + ss[2] + ss[3];
        float sumsq = sqs[0] + sqs[1] + sqs[2] + sqs[3];
        float m = sum * (1.0f / D);
        float var = sumsq * (1.0f / D) - m * m;
        mean[bid] = m;
        rstd[bid] = rsqrtf(var + 1e-5f);
    }
}

// ---------------- Kernel 2: scores (65 rows) + n_up + L directly -------------------
// grid: (16 chunks of 64 rows, 32 bh), block 256
#define XST 68  // padded LDS row stride (16B-aligned)
__global__ __launch_bounds__(256) void k_scores(const float* __restrict__ ctx,
                                                const float* __restrict__ mean,
                                                const float* __restrict__ rstd,
                                                const float* __restrict__ lnw,
                                                const float* __restrict__ lnb,
                                                const float* __restrict__ Mt,
                                                const float* __restrict__ uvec,
                                                const float* __restrict__ prior,
                                                float* __restrict__ n_up,
                                                float* __restrict__ Lg) {
    int chunk = blockIdx.x;   // 0..15
    int bh = blockIdx.y;      // 0..31
    int b = bh >> 4, h = bh & 15;
    int r0 = chunk * 64;
    int t = threadIdx.x;
    int lane = t & 63, w = t >> 6;

    __shared__ float xs[72][XST];   // normalized x rows r0-1 .. r0+65 (lr 0..66), rest 0
    __shared__ float ts[72][XST];   // t = M x
    __shared__ float spu[66], spd[66];

    // M column 'lane' -> registers (coalesced, Mt is L2-resident 16KB)
    float Mreg[64];
    #pragma unroll
    for (int e = 0; e < 64; ++e) Mreg[e] = Mt[e * 64 + lane];

    // stage normalized x (with halo); zero the pad rows
    for (int idx = t; idx < 72 * 64; idx += 256) {
        int lr = idx >> 6, c = idx & 63;
        int row = r0 - 1 + lr;
        float v = 0.0f;
        if (lr < 67 && row >= 0 && row < S) {
            float cv = ctx[((size_t)b * S + row) * D + h * 64 + c];
            v = (cv - mean[b * S + row]) * rstd[b * S + row] * lnw[h * 64 + c] + lnb[h * 64 + c];
        }
        xs[lr][c] = v;
    }
    __syncthreads();

    // ts[r][lane] = sum_e M[lane][e] * xs[r][e]; 8-row accumulators, b128 uniform reads
    for (int s8 = w; s8 < 9; s8 += 4) {
        int rb = s8 * 8;
        float acc[8] = {0, 0, 0, 0, 0, 0, 0, 0};
        #pragma unroll
        for (int eq = 0; eq < 16; ++eq) {
            #pragma unroll
            for (int rr = 0; rr < 8; ++rr) {
                float4 xv = *(const float4*)&xs[rb + rr][eq * 4];
                acc[rr] += Mreg[eq * 4 + 0] * xv.x + Mreg[eq * 4 + 1] * xv.y +
                           Mreg[eq * 4 + 2] * xv.z + Mreg[eq * 4 + 3] * xv.w;
            }
        }
        #pragma unroll
        for (int rr = 0; rr < 8; ++rr) ts[rb + rr][lane] = acc[rr];
    }
    __syncthreads();

    // score diff for local rows l (global i = r0 + l):
    //   diff_i = x_i.(t_{i+1}-t_{i-1}) + u.(x_{i+1}-x_{i-1})
    // 4 lanes per row, 16 d-values per lane, shfl-reduce within the 4-lane group.
    int part = lane & 3;
    #pragma unroll
    for (int pass = 0; pass < 2; ++pass) {
        int l = pass == 0 ? (w * 16 + (lane >> 2)) : 64;
        bool active = (pass == 0) || (w == 0 && (lane >> 2) == 0);
        int i = r0 + l;
        if (active && i < S) {
            float diff = 0.0f;
            #pragma unroll
            for (int dq = 0; dq < 4; ++dq) {
                int d0 = part * 16 + dq * 4;
                float4 xi = *(const float4*)&xs[l + 1][d0];
                float4 t2 = *(const float4*)&ts[l + 2][d0];
                float4 t0 = *(const float4*)&ts[l][d0];
                float4 x2 = *(const float4*)&xs[l + 2][d0];
                float4 x0 = *(const float4*)&xs[l][d0];
                float4 uv = *(const float4*)&uvec[d0];  // uniform, L2
                diff += xi.x * (t2.x - t0.x) + uv.x * (x2.x - x0.x);
                diff += xi.y * (t2.y - t0.y) + uv.y * (x2.y - x0.y);
                diff += xi.z * (t2.z - t0.z) + uv.z * (x2.z - x0.z);
                diff += xi.w * (t2.w - t0.w) + uv.w * (x2.w - x0.w);
            }
            diff += __shfl_down(diff, 2);
            diff += __shfl_down(diff, 1);
            if (part == 0) {
                float z = diff * (1.0f / 64.0f);
                float pu, pd;
                if (i == 0)          { pu = 1.0f; pd = 0.0f; }
                else if (i == S - 1) { pu = 0.0f; pd = 1.0f; }
                else {
                    float ez = __expf(-z);
                    pu = 1.0f / (1.0f + ez);
                    pd = 1.0f - pu;
                }
                spu[l] = pu;
                spd[l] = pd;
            }
        }
    }
    __syncthreads();

    // n_up[i] = sqrt(pu[i]*pd[i+1]+1e-4); L[i] = log(prior_blend + 1e-9)
    if (t < 64) {
        int i = r0 + t;
        float L = 0.0f;
        if (i < S - 1) {
            float nr = sqrtf(spu[t] * spd[t + 1] + 1e-4f);
            n_up[bh * S + i] = nr;
            float pr = prior[((size_t)bh * S + i) * S + i + 1];
            float N = pr + (1.0f - pr) * nr;
            L = logf(N + 1e-9f);
        }
        Lg[bh * S + i] = L;
    }
}

// ---------------- Kernel 3: pure shfl scan of L -> C --------------------------------
__global__ __launch_bounds__(1024) void k_scan(const float* __restrict__ Lg,
                                               float* __restrict__ C) {
    int bh = blockIdx.x;
    int t = threadIdx.x;
    float val = (t > 0) ? Lg[bh * S + t - 1] : 0.0f;
    int lane = t & 63, wid = t >> 6;
    #pragma unroll
    for (int off = 1; off < 64; off <<= 1) {
        float v = __shfl_up(val, off, 64);
        if (lane >= off) val += v;
    }
    __shared__ float wsum[16];
    if (lane == 63) wsum[wid] = val;
    __syncthreads();
    if (t < 16) {
        float v2 = wsum[t];
        #pragma unroll
        for (int off = 1; off < 16; off <<= 1) {
            float x = __shfl_up(v2, off, 64);
            if (t >= off) v2 += x;
        }
        wsum[t] = v2;
    }
    __syncthreads();
    float base = (wid > 0) ? wsum[wid - 1] : 0.0f;
    C[bh * S + t] = base + val;  // exclusive prefix over L
}

// ---------------- Kernel 4: big elementwise pass -> g and neibor --------------------
// grid: 4096 blocks, each handles 8 consecutive rows of one bh; thread = 4 cols.
__global__ __launch_bounds__(256) void k_out(const float* __restrict__ prior,
                                             const float* __restrict__ n_up,
                                             const float* __restrict__ C,
                                             float* __restrict__ g_out,
                                             float* __restrict__ nb_out) {
    int t = threadIdx.x;
    int bid = blockIdx.x;          // 0..4095
    int bh = bid >> 7;
    int i0 = (bid & 127) * 8;
    int j0 = t * 4;
    const float* Crow = C + bh * S;
    f32x4 c4 = *(const f32x4*)(Crow + j0);          // this thread's C[j] quad (L2)
    f32x4 ciA = *(const f32x4*)(Crow + i0);         // C[i] for the block's 8 rows
    f32x4 ciB = *(const f32x4*)(Crow + i0 + 4);
    #pragma unroll
    for (int r = 0; r < 8; ++r) {
        int i = i0 + r;
        float Ci = (r < 4) ? ciA[r] : ciB[r - 4];
        size_t rowbase = ((size_t)bh * S + i) * S;
        f32x4 p4 = __builtin_nontemporal_load((const f32x4*)(prior + rowbase + j0));
        f32x4 nb, gg;
        // fast path: C monotone non-increasing -> g = exp(-|C[j]-C[i]|)+1e-4 for j!=i
        #pragma unroll
        for (int l = 0; l < 4; ++l) {
            nb[l] = fmaf(0.99f, p4[l], 0.01f);
            gg[l] = __expf(-fabsf(c4[l] - Ci)) + 1e-4f;
        }
        // slow fixup only where [i-1,i+1] intersects [j0,j0+3] (~1 wave per row)
        if (i - 1 <= j0 + 3 && i + 1 >= j0) {
            float nup_i  = (i < S - 1) ? n_up[bh * S + i] : 0.0f;
            float nup_im = (i > 0)     ? n_up[bh * S + i - 1] : 0.0f;
            #pragma unroll
            for (int l = 0; l < 4; ++l) {
                int j = j0 + l;
                if (j == i + 1) nb[l] = p4[l] + (1.0f - p4[l]) * nup_i;
                if (j == i - 1) nb[l] = p4[l] + (1.0f - p4[l]) * nup_im;
                if (j == i)     gg[l] = nb[l];   // diag: g = neibor
            }
        }
        __builtin_nontemporal_store(gg, (f32x4*)(g_out + rowbase + j0));
        __builtin_nontemporal_store(nb, (f32x4*)(nb_out + rowbase + j0));
    }
}

extern "C" void kernel_launch(void* const* d_in, const int* in_sizes, int n_in,
                              void* d_out, int out_size, void* d_ws, size_t ws_size,
                              hipStream_t stream) {
    const float* ctx   = (const float*)d_in[0];
    // d_in[1] = eos_mask (all true) -- unused
    const float* prior = (const float*)d_in[2];
    const float* lnw   = (const float*)d_in[3];
    const float* lnb   = (const float*)d_in[4];
    const float* wk    = (const float*)d_in[5];
    // d_in[6] = bk -- cancels in the score difference
    const float* wq    = (const float*)d_in[7];
    const float* bq    = (const float*)d_in[8];

    float* ws = (float*)d_ws;
    float* mean = ws;                  // 2048
    float* rstd = ws + 2048;           // 2048
    float* Mt   = ws + 4096;           // 4096
    float* uvec = ws + 8192;           // 64 (pad to 256)
    float* n_up = ws + 8448;           // 32*1024
    float* Lg   = ws + 8448 + 32768;   // 32*1024
    float* C    = ws + 8448 + 65536;   // 32*1024

    float* g_out  = (float*)d_out;
    float* nb_out = (float*)d_out + (size_t)BS * H * S * S;

    k_ln_prep<<<BS * S + 4, 256, 0, stream>>>(ctx, wk, wq, bq, mean, rstd, Mt, uvec);
    k_scores<<<dim3(16, BS * H), 256, 0, stream>>>(ctx, mean, rstd, lnw, lnb, Mt, uvec,
                                                   prior, n_up, Lg);
    k_scan<<<BS * H, 1024, 0, stream>>>(Lg, C);
    k_out<<<BS * H * S / 8, 256, 0, stream>>>(prior, n_up, C, g_out, nb_out);
}

// Round 7
// 105.258 us; speedup vs baseline: 1.2674x; 1.0478x over previous
//
#include <hip/hip_runtime.h>
#include <hip/hip_bf16.h>

#define S 1024
#define H 16
#define BS 2
#define D 1024

typedef float f32x4 __attribute__((ext_vector_type(4)));

// ---------------- Kernel 1: LN stats (blocks 0..2047) + M/u prep (blocks 2048..2051) --
// M[a][e] = sum_d Wq[d][a]*Wk[d][e]  (stored transposed: Mt[e*64+a])
// u[e]    = sum_d bq[d]*Wk[d][e]
__global__ __launch_bounds__(256) void k_ln_prep(const float* __restrict__ ctx,
                                                 const float* __restrict__ wk,
                                                 const float* __restrict__ wq,
                                                 const float* __restrict__ bq,
                                                 float* __restrict__ mean,
                                                 float* __restrict__ rstd,
                                                 float* __restrict__ Mt,
                                                 float* __restrict__ uvec) {
    __shared__ float sh[2 * 64 * 65];  // prep: Wq | Wk (padded).  LN: first 8 floats.
    int t = threadIdx.x;
    int bid = blockIdx.x;

    if (bid >= BS * S) {
        // ---- prep path: 4 blocks, each handles 16 values of e ----
        int p = bid - BS * S;  // 0..3
        float* WqL = sh;            // [64][65]
        float* WkL = sh + 64 * 65;  // [64][65]
        for (int idx = t; idx < 4096; idx += 256) {
            int d = idx >> 6, c = idx & 63;
            WqL[d * 65 + c] = wq[idx];
            WkL[d * 65 + c] = wk[idx];
        }
        __syncthreads();
        int a = t & 63, sub = t >> 6;
        for (int ee = sub; ee < 16; ee += 4) {
            int e = p * 16 + ee;
            float acc = 0.0f;
            #pragma unroll 8
            for (int d = 0; d < 64; ++d) acc += WqL[d * 65 + a] * WkL[d * 65 + e];
            Mt[e * 64 + a] = acc;
        }
        if (p == 0 && t < 64) {
            float acc = 0.0f;
            #pragma unroll 8
            for (int d = 0; d < 64; ++d) acc += bq[d] * WkL[d * 65 + t];
            uvec[t] = acc;
        }
        return;
    }

    // ---- LN stats path ----
    const float* x = ctx + (size_t)bid * D;
    float4 v = *(const float4*)(x + t * 4);
    float s = v.x + v.y + v.z + v.w;
    float sq = v.x * v.x + v.y * v.y + v.z * v.z + v.w * v.w;
    #pragma unroll
    for (int off = 32; off > 0; off >>= 1) {
        s += __shfl_down(s, off);
        sq += __shfl_down(sq, off);
    }
    float* ss = sh;       // [4]
    float* sqs = sh + 4;  // [4]
    int w = t >> 6;
    if ((t & 63) == 0) { ss[w] = s; sqs[w] = sq; }
    __syncthreads();
    if (t == 0) {
        float sum = ss[0] + ss[1] + ss[2] + ss[3];
        float sumsq = sqs[0] + sqs[1] + sqs[2] + sqs[3];
        float m = sum * (1.0f / D);
        float var = sumsq * (1.0f / D) - m * m;
        mean[bid] = m;
        rstd[bid] = rsqrtf(var + 1e-5f);
    }
}

// ---------------- Kernel 2: scores (65 rows) + n_up + L directly -------------------
// grid: (16 chunks of 64 rows, 32 bh), block 256
#define XST 68  // padded LDS row stride (16B-aligned)
__global__ __launch_bounds__(256) void k_scores(const float* __restrict__ ctx,
                                                const float* __restrict__ mean,
                                                const float* __restrict__ rstd,
                                                const float* __restrict__ lnw,
                                                const float* __restrict__ lnb,
                                                const float* __restrict__ Mt,
                                                const float* __restrict__ uvec,
                                                const float* __restrict__ prior,
                                                float* __restrict__ n_up,
                                                float* __restrict__ Lg) {
    int chunk = blockIdx.x;   // 0..15
    int bh = blockIdx.y;      // 0..31
    int b = bh >> 4, h = bh & 15;
    int r0 = chunk * 64;
    int t = threadIdx.x;
    int lane = t & 63, w = t >> 6;

    __shared__ float xs[72][XST];   // normalized x rows r0-1 .. r0+65 (lr 0..66), rest 0
    __shared__ float ts[72][XST];   // t = M x
    __shared__ float spu[66], spd[66];
    __shared__ float lwL[64], lbL[64], muL[72], rsL[72];

    // M column 'lane' -> registers (coalesced, Mt is L2-resident 16KB)
    float Mreg[64];
    #pragma unroll
    for (int e = 0; e < 64; ++e) Mreg[e] = Mt[e * 64 + lane];

    // small params -> LDS (one-time)
    if (t < 64) {
        lwL[t] = lnw[h * 64 + t];
        lbL[t] = lnb[h * 64 + t];
    } else if (t < 64 + 72) {
        int lr = t - 64;
        int row = r0 - 1 + lr;
        bool ok = (lr < 67) && (row >= 0) && (row < S);
        muL[lr] = ok ? mean[b * S + row] : 0.0f;
        rsL[lr] = ok ? rstd[b * S + row] : 0.0f;
    }

    // stage RAW ctx slab as f32x4 (rows r0-1 .. r0+65); zero pads
    for (int idx = t; idx < 72 * 16; idx += 256) {
        int lr = idx >> 4, qc = idx & 15;
        int row = r0 - 1 + lr;
        f32x4 v = {0.f, 0.f, 0.f, 0.f};
        if (lr < 67 && row >= 0 && row < S)
            v = *(const f32x4*)(ctx + ((size_t)b * S + row) * D + h * 64 + qc * 4);
        *(f32x4*)&xs[lr][qc * 4] = v;
    }
    __syncthreads();

    // normalize in place (LDS-resident params)
    for (int idx = t; idx < 72 * 16; idx += 256) {
        int lr = idx >> 4, qc = idx & 15;
        int row = r0 - 1 + lr;
        if (lr < 67 && row >= 0 && row < S) {
            f32x4 v = *(f32x4*)&xs[lr][qc * 4];
            float m = muL[lr], r = rsL[lr];
            f32x4 wv = *(f32x4*)&lwL[qc * 4];
            f32x4 bv = *(f32x4*)&lbL[qc * 4];
            v = (v - m) * r * wv + bv;
            *(f32x4*)&xs[lr][qc * 4] = v;
        }
    }
    __syncthreads();

    // ts[r][lane] = sum_e M[lane][e] * xs[r][e]; 8-row accumulators, b128 uniform reads
    for (int s8 = w; s8 < 9; s8 += 4) {
        int rb = s8 * 8;
        float acc[8] = {0, 0, 0, 0, 0, 0, 0, 0};
        #pragma unroll
        for (int eq = 0; eq < 16; ++eq) {
            #pragma unroll
            for (int rr = 0; rr < 8; ++rr) {
                f32x4 xv = *(const f32x4*)&xs[rb + rr][eq * 4];
                acc[rr] += Mreg[eq * 4 + 0] * xv.x + Mreg[eq * 4 + 1] * xv.y +
                           Mreg[eq * 4 + 2] * xv.z + Mreg[eq * 4 + 3] * xv.w;
            }
        }
        #pragma unroll
        for (int rr = 0; rr < 8; ++rr) ts[rb + rr][lane] = acc[rr];
    }
    __syncthreads();

    // score diff for local rows l (global i = r0 + l):
    //   diff_i = x_i.(t_{i+1}-t_{i-1}) + u.(x_{i+1}-x_{i-1})
    // 4 lanes per row, 16 d-values per lane, shfl-reduce within the 4-lane group.
    int part = lane & 3;
    #pragma unroll
    for (int pass = 0; pass < 2; ++pass) {
        int l = pass == 0 ? (w * 16 + (lane >> 2)) : 64;
        bool active = (pass == 0) || (w == 0 && (lane >> 2) == 0);
        int i = r0 + l;
        if (active && i < S) {
            float diff = 0.0f;
            #pragma unroll
            for (int dq = 0; dq < 4; ++dq) {
                int d0 = part * 16 + dq * 4;
                f32x4 xi = *(const f32x4*)&xs[l + 1][d0];
                f32x4 t2 = *(const f32x4*)&ts[l + 2][d0];
                f32x4 t0 = *(const f32x4*)&ts[l][d0];
                f32x4 x2 = *(const f32x4*)&xs[l + 2][d0];
                f32x4 x0 = *(const f32x4*)&xs[l][d0];
                f32x4 uv = *(const f32x4*)&uvec[d0];  // uniform, L2
                diff += xi.x * (t2.x - t0.x) + uv.x * (x2.x - x0.x);
                diff += xi.y * (t2.y - t0.y) + uv.y * (x2.y - x0.y);
                diff += xi.z * (t2.z - t0.z) + uv.z * (x2.z - x0.z);
                diff += xi.w * (t2.w - t0.w) + uv.w * (x2.w - x0.w);
            }
            diff += __shfl_down(diff, 2);
            diff += __shfl_down(diff, 1);
            if (part == 0) {
                float z = diff * (1.0f / 64.0f);
                float pu, pd;
                if (i == 0)          { pu = 1.0f; pd = 0.0f; }
                else if (i == S - 1) { pu = 0.0f; pd = 1.0f; }
                else {
                    float ez = __expf(-z);
                    pu = 1.0f / (1.0f + ez);
                    pd = 1.0f - pu;
                }
                spu[l] = pu;
                spd[l] = pd;
            }
        }
    }
    __syncthreads();

    // n_up[i] = sqrt(pu[i]*pd[i+1]+1e-4); L[i] = log(prior_blend + 1e-9)
    if (t < 64) {
        int i = r0 + t;
        float L = 0.0f;
        if (i < S - 1) {
            float nr = sqrtf(spu[t] * spd[t + 1] + 1e-4f);
            n_up[bh * S + i] = nr;
            float pr = prior[((size_t)bh * S + i) * S + i + 1];
            float N = pr + (1.0f - pr) * nr;
            L = logf(N + 1e-9f);
        }
        Lg[bh * S + i] = L;
    }
}

// ---------------- Kernel 3: in-block scan of Lg + big elementwise pass --------------
// grid: 4096 blocks, each handles 8 consecutive rows of one bh; thread = 4 cols.
__global__ __launch_bounds__(256) void k_out(const float* __restrict__ prior,
                                             const float* __restrict__ n_up,
                                             const float* __restrict__ Lg,
                                             float* __restrict__ g_out,
                                             float* __restrict__ nb_out) {
    int t = threadIdx.x;
    int bid = blockIdx.x;          // 0..4095
    int bh = bid >> 7;
    int i0 = (bid & 127) * 8;
    int j0 = t * 4;
    int lane = t & 63, w = t >> 6;

    __shared__ float Csh[1024];
    __shared__ float wtot[4];

    // ---- block-wide exclusive scan of Lg row, pre-scaled by log2(e) ----
    const float LOG2E = 1.4426950408889634f;
    f32x4 q = *(const f32x4*)(Lg + bh * S + j0);
    float e1 = q.x, e2 = q.x + q.y, e3 = e2 + q.z;
    float tot = e3 + q.w;
    float incl = tot;
    #pragma unroll
    for (int off = 1; off < 64; off <<= 1) {
        float v = __shfl_up(incl, off, 64);
        if (lane >= off) incl += v;
    }
    if (lane == 63) wtot[w] = incl;
    __syncthreads();
    float base = incl - tot;          // exclusive within wave
    if (w > 0) base += wtot[0];
    if (w > 1) base += wtot[1];
    if (w > 2) base += wtot[2];
    f32x4 c4;                          // C2[j] = C[j] * log2(e) for this thread's quad
    c4.x = base * LOG2E;
    c4.y = (base + e1) * LOG2E;
    c4.z = (base + e2) * LOG2E;
    c4.w = (base + e3) * LOG2E;
    *(f32x4*)&Csh[j0] = c4;
    __syncthreads();

    f32x4 ciA = *(const f32x4*)&Csh[i0];       // C2[i] for the block's 8 rows (bcast)
    f32x4 ciB = *(const f32x4*)&Csh[i0 + 4];

    #pragma unroll
    for (int r = 0; r < 8; ++r) {
        int i = i0 + r;
        float Ci = (r < 4) ? ciA[r] : ciB[r - 4];
        size_t rowbase = ((size_t)bh * S + i) * S;
        f32x4 p4 = __builtin_nontemporal_load((const f32x4*)(prior + rowbase + j0));
        f32x4 nb, gg;
        // fast path: C monotone non-increasing -> g = exp2(-|C2[j]-C2[i]|)+1e-4, j!=i
        #pragma unroll
        for (int l = 0; l < 4; ++l) {
            nb[l] = fmaf(0.99f, p4[l], 0.01f);
            gg[l] = exp2f(-fabsf(c4[l] - Ci)) + 1e-4f;
        }
        // slow fixup only where [i-1,i+1] intersects [j0,j0+3] (~1 wave per row)
        if (i - 1 <= j0 + 3 && i + 1 >= j0) {
            float nup_i  = (i < S - 1) ? n_up[bh * S + i] : 0.0f;
            float nup_im = (i > 0)     ? n_up[bh * S + i - 1] : 0.0f;
            #pragma unroll
            for (int l = 0; l < 4; ++l) {
                int j = j0 + l;
                if (j == i + 1) nb[l] = p4[l] + (1.0f - p4[l]) * nup_i;
                if (j == i - 1) nb[l] = p4[l] + (1.0f - p4[l]) * nup_im;
                if (j == i)     gg[l] = nb[l];   // diag: g = neibor
            }
        }
        __builtin_nontemporal_store(gg, (f32x4*)(g_out + rowbase + j0));
        __builtin_nontemporal_store(nb, (f32x4*)(nb_out + rowbase + j0));
    }
}

extern "C" void kernel_launch(void* const* d_in, const int* in_sizes, int n_in,
                              void* d_out, int out_size, void* d_ws, size_t ws_size,
                              hipStream_t stream) {
    const float* ctx   = (const float*)d_in[0];
    // d_in[1] = eos_mask (all true) -- unused
    const float* prior = (const float*)d_in[2];
    const float* lnw   = (const float*)d_in[3];
    const float* lnb   = (const float*)d_in[4];
    const float* wk    = (const float*)d_in[5];
    // d_in[6] = bk -- cancels in the score difference
    const float* wq    = (const float*)d_in[7];
    const float* bq    = (const float*)d_in[8];

    float* ws = (float*)d_ws;
    float* mean = ws;                  // 2048
    float* rstd = ws + 2048;           // 2048
    float* Mt   = ws + 4096;           // 4096
    float* uvec = ws + 8192;           // 64 (pad to 256)
    float* n_up = ws + 8448;           // 32*1024
    float* Lg   = ws + 8448 + 32768;   // 32*1024

    float* g_out  = (float*)d_out;
    float* nb_out = (float*)d_out + (size_t)BS * H * S * S;

    k_ln_prep<<<BS * S + 4, 256, 0, stream>>>(ctx, wk, wq, bq, mean, rstd, Mt, uvec);
    k_scores<<<dim3(16, BS * H), 256, 0, stream>>>(ctx, mean, rstd, lnw, lnb, Mt, uvec,
                                                   prior, n_up, Lg);
    k_out<<<BS * H * S / 8, 256, 0, stream>>>(prior, n_up, Lg, g_out, nb_out);
}

// Round 8
// 101.636 us; speedup vs baseline: 1.3126x; 1.0356x over previous
//
#include <hip/hip_runtime.h>
#include <hip/hip_bf16.h>

#define S 1024
#define H 16
#define BS 2
#define D 1024

typedef float f32x4 __attribute__((ext_vector_type(4)));

// ---------------- Kernel 1: LN stats (blocks 0..2047) + M/u prep (blocks 2048..2051) --
// M[a][e] = sum_d Wq[d][a]*Wk[d][e]  (stored transposed: Mt[e*64+a])
// u[e]    = sum_d bq[d]*Wk[d][e]
__global__ __launch_bounds__(256) void k_ln_prep(const float* __restrict__ ctx,
                                                 const float* __restrict__ wk,
                                                 const float* __restrict__ wq,
                                                 const float* __restrict__ bq,
                                                 float* __restrict__ mean,
                                                 float* __restrict__ rstd,
                                                 float* __restrict__ Mt,
                                                 float* __restrict__ uvec) {
    __shared__ float sh[2 * 64 * 65];  // prep: Wq | Wk (padded).  LN: first 8 floats.
    int t = threadIdx.x;
    int bid = blockIdx.x;

    if (bid >= BS * S) {
        // ---- prep path: 4 blocks, each handles 16 values of e ----
        int p = bid - BS * S;  // 0..3
        float* WqL = sh;            // [64][65]
        float* WkL = sh + 64 * 65;  // [64][65]
        for (int idx = t; idx < 4096; idx += 256) {
            int d = idx >> 6, c = idx & 63;
            WqL[d * 65 + c] = wq[idx];
            WkL[d * 65 + c] = wk[idx];
        }
        __syncthreads();
        int a = t & 63, sub = t >> 6;
        for (int ee = sub; ee < 16; ee += 4) {
            int e = p * 16 + ee;
            float acc = 0.0f;
            #pragma unroll 8
            for (int d = 0; d < 64; ++d) acc += WqL[d * 65 + a] * WkL[d * 65 + e];
            Mt[e * 64 + a] = acc;
        }
        if (p == 0 && t < 64) {
            float acc = 0.0f;
            #pragma unroll 8
            for (int d = 0; d < 64; ++d) acc += bq[d] * WkL[d * 65 + t];
            uvec[t] = acc;
        }
        return;
    }

    // ---- LN stats path ----
    const float* x = ctx + (size_t)bid * D;
    float4 v = *(const float4*)(x + t * 4);
    float s = v.x + v.y + v.z + v.w;
    float sq = v.x * v.x + v.y * v.y + v.z * v.z + v.w * v.w;
    #pragma unroll
    for (int off = 32; off > 0; off >>= 1) {
        s += __shfl_down(s, off);
        sq += __shfl_down(sq, off);
    }
    float* ss = sh;       // [4]
    float* sqs = sh + 4;  // [4]
    int w = t >> 6;
    if ((t & 63) == 0) { ss[w] = s; sqs[w] = sq; }
    __syncthreads();
    if (t == 0) {
        float sum = ss[0] + ss[1] + ss[2] + ss[3];
        float sumsq = sqs[0] + sqs[1] + sqs[2] + sqs[3];
        float m = sum * (1.0f / D);
        float var = sumsq * (1.0f / D) - m * m;
        mean[bid] = m;
        rstd[bid] = rsqrtf(var + 1e-5f);
    }
}

// ---------------- Kernel 2: scores (65 rows) + n_up + L directly -------------------
// grid: (16 chunks of 64 rows, 32 bh), block 256
#define XST 68  // padded LDS row stride (16B-aligned)
__global__ __launch_bounds__(256) void k_scores(const float* __restrict__ ctx,
                                                const float* __restrict__ mean,
                                                const float* __restrict__ rstd,
                                                const float* __restrict__ lnw,
                                                const float* __restrict__ lnb,
                                                const float* __restrict__ Mt,
                                                const float* __restrict__ uvec,
                                                const float* __restrict__ prior,
                                                float* __restrict__ n_up,
                                                float* __restrict__ Lg) {
    int chunk = blockIdx.x;   // 0..15
    int bh = blockIdx.y;      // 0..31
    int b = bh >> 4, h = bh & 15;
    int r0 = chunk * 64;
    int t = threadIdx.x;
    int lane = t & 63, w = t >> 6;

    __shared__ float xs[72][XST];   // normalized x rows r0-1 .. r0+65 (lr 0..66), rest 0
    __shared__ float ts[72][XST];   // t = M x
    __shared__ float spu[66], spd[66];

    // M column 'lane' -> registers (coalesced, Mt is L2-resident 16KB)
    float Mreg[64];
    #pragma unroll
    for (int e = 0; e < 64; ++e) Mreg[e] = Mt[e * 64 + lane];

    // fused stage + normalize (mean/rstd/lnw/lnb are L2-hot, read directly)
    for (int idx = t; idx < 72 * 16; idx += 256) {
        int lr = idx >> 4, qc = idx & 15;
        int row = r0 - 1 + lr;
        f32x4 v = {0.f, 0.f, 0.f, 0.f};
        if (lr < 67 && row >= 0 && row < S) {
            v = *(const f32x4*)(ctx + ((size_t)b * S + row) * D + h * 64 + qc * 4);
            float m = mean[b * S + row], r = rstd[b * S + row];
            f32x4 wv = *(const f32x4*)(lnw + h * 64 + qc * 4);
            f32x4 bv = *(const f32x4*)(lnb + h * 64 + qc * 4);
            v = (v - m) * r * wv + bv;
        }
        *(f32x4*)&xs[lr][qc * 4] = v;
    }
    __syncthreads();

    // ts[r][lane] = sum_e M[lane][e] * xs[r][e]
    // balanced: wave w owns rows lr = w*17 .. w*17+16 (covers 0..67)
    {
        int rb = w * 17;
        float acc[17];
        #pragma unroll
        for (int rr = 0; rr < 17; ++rr) acc[rr] = 0.0f;
        #pragma unroll
        for (int eq = 0; eq < 16; ++eq) {
            #pragma unroll
            for (int rr = 0; rr < 17; ++rr) {
                f32x4 xv = *(const f32x4*)&xs[rb + rr][eq * 4];  // uniform broadcast
                acc[rr] += Mreg[eq * 4 + 0] * xv.x + Mreg[eq * 4 + 1] * xv.y +
                           Mreg[eq * 4 + 2] * xv.z + Mreg[eq * 4 + 3] * xv.w;
            }
        }
        #pragma unroll
        for (int rr = 0; rr < 17; ++rr) ts[rb + rr][lane] = acc[rr];
    }
    __syncthreads();

    // score diff for local rows l (global i = r0 + l):
    //   diff_i = x_i.(t_{i+1}-t_{i-1}) + u.(x_{i+1}-x_{i-1})
    // 4 lanes per row, 16 d-values per lane, shfl-reduce within the 4-lane group.
    int part = lane & 3;
    #pragma unroll
    for (int pass = 0; pass < 2; ++pass) {
        int l = pass == 0 ? (w * 16 + (lane >> 2)) : 64;
        bool active = (pass == 0) || (w == 0 && (lane >> 2) == 0);
        int i = r0 + l;
        if (active && i < S) {
            float diff = 0.0f;
            #pragma unroll
            for (int dq = 0; dq < 4; ++dq) {
                int d0 = part * 16 + dq * 4;
                f32x4 xi = *(const f32x4*)&xs[l + 1][d0];
                f32x4 t2 = *(const f32x4*)&ts[l + 2][d0];
                f32x4 t0 = *(const f32x4*)&ts[l][d0];
                f32x4 x2 = *(const f32x4*)&xs[l + 2][d0];
                f32x4 x0 = *(const f32x4*)&xs[l][d0];
                f32x4 uv = *(const f32x4*)&uvec[d0];  // uniform, L2
                diff += xi.x * (t2.x - t0.x) + uv.x * (x2.x - x0.x);
                diff += xi.y * (t2.y - t0.y) + uv.y * (x2.y - x0.y);
                diff += xi.z * (t2.z - t0.z) + uv.z * (x2.z - x0.z);
                diff += xi.w * (t2.w - t0.w) + uv.w * (x2.w - x0.w);
            }
            diff += __shfl_down(diff, 2);
            diff += __shfl_down(diff, 1);
            if (part == 0) {
                float z = diff * (1.0f / 64.0f);
                float pu, pd;
                if (i == 0)          { pu = 1.0f; pd = 0.0f; }
                else if (i == S - 1) { pu = 0.0f; pd = 1.0f; }
                else {
                    float ez = __expf(-z);
                    pu = 1.0f / (1.0f + ez);
                    pd = 1.0f - pu;
                }
                spu[l] = pu;
                spd[l] = pd;
            }
        }
    }
    __syncthreads();

    // n_up[i] = sqrt(pu[i]*pd[i+1]+1e-4); L[i] = log(prior_blend + 1e-9)
    if (t < 64) {
        int i = r0 + t;
        float L = 0.0f;
        if (i < S - 1) {
            float nr = sqrtf(spu[t] * spd[t + 1] + 1e-4f);
            n_up[bh * S + i] = nr;
            float pr = prior[((size_t)bh * S + i) * S + i + 1];
            float N = pr + (1.0f - pr) * nr;
            L = logf(N + 1e-9f);
        }
        Lg[bh * S + i] = L;
    }
}

// ---------------- Kernel 3: in-block scan of Lg + big elementwise pass --------------
// grid: 4096 blocks, each handles 8 consecutive rows of one bh; thread = 4 cols.
__global__ __launch_bounds__(256) void k_out(const float* __restrict__ prior,
                                             const float* __restrict__ n_up,
                                             const float* __restrict__ Lg,
                                             float* __restrict__ g_out,
                                             float* __restrict__ nb_out) {
    int t = threadIdx.x;
    int bid = blockIdx.x;          // 0..4095
    int bh = bid >> 7;
    int i0 = (bid & 127) * 8;
    int j0 = t * 4;
    int lane = t & 63, w = t >> 6;

    __shared__ float Csh[1024];
    __shared__ float wtot[4];

    // ---- block-wide exclusive scan of Lg row, pre-scaled by log2(e) ----
    const float LOG2E = 1.4426950408889634f;
    f32x4 q = *(const f32x4*)(Lg + bh * S + j0);
    float e1 = q.x, e2 = q.x + q.y, e3 = e2 + q.z;
    float tot = e3 + q.w;
    float incl = tot;
    #pragma unroll
    for (int off = 1; off < 64; off <<= 1) {
        float v = __shfl_up(incl, off, 64);
        if (lane >= off) incl += v;
    }
    if (lane == 63) wtot[w] = incl;
    __syncthreads();
    float base = incl - tot;          // exclusive within wave
    if (w > 0) base += wtot[0];
    if (w > 1) base += wtot[1];
    if (w > 2) base += wtot[2];
    f32x4 c4;                          // C2[j] = C[j] * log2(e) for this thread's quad
    c4.x = base * LOG2E;
    c4.y = (base + e1) * LOG2E;
    c4.z = (base + e2) * LOG2E;
    c4.w = (base + e3) * LOG2E;
    *(f32x4*)&Csh[j0] = c4;
    __syncthreads();

    f32x4 ciA = *(const f32x4*)&Csh[i0];       // C2[i] for the block's 8 rows (bcast)
    f32x4 ciB = *(const f32x4*)&Csh[i0 + 4];

    #pragma unroll
    for (int r = 0; r < 8; ++r) {
        int i = i0 + r;
        float Ci = (r < 4) ? ciA[r] : ciB[r - 4];
        size_t rowbase = ((size_t)bh * S + i) * S;
        f32x4 p4 = __builtin_nontemporal_load((const f32x4*)(prior + rowbase + j0));
        f32x4 nb, gg;
        // fast path: C monotone non-increasing -> g = exp2(-|C2[j]-C2[i]|)+1e-4, j!=i
        #pragma unroll
        for (int l = 0; l < 4; ++l) {
            nb[l] = fmaf(0.99f, p4[l], 0.01f);
            gg[l] = exp2f(-fabsf(c4[l] - Ci)) + 1e-4f;
        }
        // slow fixup only where [i-1,i+1] intersects [j0,j0+3] (~1 wave per row)
        if (i - 1 <= j0 + 3 && i + 1 >= j0) {
            float nup_i  = (i < S - 1) ? n_up[bh * S + i] : 0.0f;
            float nup_im = (i > 0)     ? n_up[bh * S + i - 1] : 0.0f;
            #pragma unroll
            for (int l = 0; l < 4; ++l) {
                int j = j0 + l;
                if (j == i + 1) nb[l] = p4[l] + (1.0f - p4[l]) * nup_i;
                if (j == i - 1) nb[l] = p4[l] + (1.0f - p4[l]) * nup_im;
                if (j == i)     gg[l] = nb[l];   // diag: g = neibor
            }
        }
        __builtin_nontemporal_store(gg, (f32x4*)(g_out + rowbase + j0));
        __builtin_nontemporal_store(nb, (f32x4*)(nb_out + rowbase + j0));
    }
}

extern "C" void kernel_launch(void* const* d_in, const int* in_sizes, int n_in,
                              void* d_out, int out_size, void* d_ws, size_t ws_size,
                              hipStream_t stream) {
    const float* ctx   = (const float*)d_in[0];
    // d_in[1] = eos_mask (all true) -- unused
    const float* prior = (const float*)d_in[2];
    const float* lnw   = (const float*)d_in[3];
    const float* lnb   = (const float*)d_in[4];
    const float* wk    = (const float*)d_in[5];
    // d_in[6] = bk -- cancels in the score difference
    const float* wq    = (const float*)d_in[7];
    const float* bq    = (const float*)d_in[8];

    float* ws = (float*)d_ws;
    float* mean = ws;                  // 2048
    float* rstd = ws + 2048;           // 2048
    float* Mt   = ws + 4096;           // 4096
    float* uvec = ws + 8192;           // 64 (pad to 256)
    float* n_up = ws + 8448;           // 32*1024
    float* Lg   = ws + 8448 + 32768;   // 32*1024

    float* g_out  = (float*)d_out;
    float* nb_out = (float*)d_out + (size_t)BS * H * S * S;

    k_ln_prep<<<BS * S + 4, 256, 0, stream>>>(ctx, wk, wq, bq, mean, rstd, Mt, uvec);
    k_scores<<<dim3(16, BS * H), 256, 0, stream>>>(ctx, mean, rstd, lnw, lnb, Mt, uvec,
                                                   prior, n_up, Lg);
    k_out<<<BS * H * S / 8, 256, 0, stream>>>(prior, n_up, Lg, g_out, nb_out);
}

// Round 9
// 95.674 us; speedup vs baseline: 1.3944x; 1.0623x over previous
//
#include <hip/hip_runtime.h>
#include <hip/hip_bf16.h>

#define S 1024
#define H 16
#define BS 2
#define D 1024

typedef float f32x4 __attribute__((ext_vector_type(4)));

// ---------------- Kernel 1: LN stats (blocks 0..2047) + M/u prep (blocks 2048..2051) --
// M[a][e] = sum_d Wq[d][a]*Wk[d][e]  (stored transposed: Mt[e*64+a])
// u[e]    = sum_d bq[d]*Wk[d][e]
__global__ __launch_bounds__(256) void k_ln_prep(const float* __restrict__ ctx,
                                                 const float* __restrict__ wk,
                                                 const float* __restrict__ wq,
                                                 const float* __restrict__ bq,
                                                 float* __restrict__ mean,
                                                 float* __restrict__ rstd,
                                                 float* __restrict__ Mt,
                                                 float* __restrict__ uvec) {
    __shared__ float sh[2 * 64 * 65];  // prep: Wq | Wk (padded).  LN: first 8 floats.
    int t = threadIdx.x;
    int bid = blockIdx.x;

    if (bid >= BS * S) {
        // ---- prep path: 4 blocks, each handles 16 values of e ----
        int p = bid - BS * S;  // 0..3
        float* WqL = sh;            // [64][65]
        float* WkL = sh + 64 * 65;  // [64][65]
        for (int idx = t; idx < 4096; idx += 256) {
            int d = idx >> 6, c = idx & 63;
            WqL[d * 65 + c] = wq[idx];
            WkL[d * 65 + c] = wk[idx];
        }
        __syncthreads();
        int a = t & 63, sub = t >> 6;
        for (int ee = sub; ee < 16; ee += 4) {
            int e = p * 16 + ee;
            float acc = 0.0f;
            #pragma unroll 8
            for (int d = 0; d < 64; ++d) acc += WqL[d * 65 + a] * WkL[d * 65 + e];
            Mt[e * 64 + a] = acc;
        }
        if (p == 0 && t < 64) {
            float acc = 0.0f;
            #pragma unroll 8
            for (int d = 0; d < 64; ++d) acc += bq[d] * WkL[d * 65 + t];
            uvec[t] = acc;
        }
        return;
    }

    // ---- LN stats path ----
    const float* x = ctx + (size_t)bid * D;
    float4 v = *(const float4*)(x + t * 4);
    float s = v.x + v.y + v.z + v.w;
    float sq = v.x * v.x + v.y * v.y + v.z * v.z + v.w * v.w;
    #pragma unroll
    for (int off = 32; off > 0; off >>= 1) {
        s += __shfl_down(s, off);
        sq += __shfl_down(sq, off);
    }
    float* ss = sh;       // [4]
    float* sqs = sh + 4;  // [4]
    int w = t >> 6;
    if ((t & 63) == 0) { ss[w] = s; sqs[w] = sq; }
    __syncthreads();
    if (t == 0) {
        float sum = ss[0] + ss[1] + ss[2] + ss[3];
        float sumsq = sqs[0] + sqs[1] + sqs[2] + sqs[3];
        float m = sum * (1.0f / D);
        float var = sumsq * (1.0f / D) - m * m;
        mean[bid] = m;
        rstd[bid] = rsqrtf(var + 1e-5f);
    }
}

// ---------------- Kernel 2: scores (33 rows) + n_up + L directly -------------------
// grid: (32 chunks of 32 rows, 32 bh), block 256, ~4 blocks/CU
#define XST 68  // padded LDS row stride (16B-aligned)
__global__ __launch_bounds__(256) void k_scores(const float* __restrict__ ctx,
                                                const float* __restrict__ mean,
                                                const float* __restrict__ rstd,
                                                const float* __restrict__ lnw,
                                                const float* __restrict__ lnb,
                                                const float* __restrict__ Mt,
                                                const float* __restrict__ uvec,
                                                const float* __restrict__ prior,
                                                float* __restrict__ n_up,
                                                float* __restrict__ Lg) {
    int chunk = blockIdx.x;   // 0..31
    int bh = blockIdx.y;      // 0..31
    int b = bh >> 4, h = bh & 15;
    int r0 = chunk * 32;
    int t = threadIdx.x;
    int lane = t & 63, w = t >> 6;

    __shared__ float xs[36][XST];   // normalized x rows r0-1 .. r0+33 (lr 0..34), pad 35
    __shared__ float ts[36][XST];   // t = M x
    __shared__ float spu[34], spd[34];

    // prefetch prior superdiagonal early (latency hides under staging+matvec)
    float pr_pre = 0.0f;
    int i_pr = r0 + t;
    if (t < 32 && i_pr < S - 1)
        pr_pre = prior[((size_t)bh * S + i_pr) * S + i_pr + 1];

    // M column 'lane' -> registers (coalesced, Mt is L2-resident 16KB)
    float Mreg[64];
    #pragma unroll
    for (int e = 0; e < 64; ++e) Mreg[e] = Mt[e * 64 + lane];

    // fused stage + normalize (mean/rstd/lnw/lnb are L2-hot, read directly)
    for (int idx = t; idx < 36 * 16; idx += 256) {
        int lr = idx >> 4, qc = idx & 15;
        int row = r0 - 1 + lr;
        f32x4 v = {0.f, 0.f, 0.f, 0.f};
        if (lr < 35 && row >= 0 && row < S) {
            v = *(const f32x4*)(ctx + ((size_t)b * S + row) * D + h * 64 + qc * 4);
            float m = mean[b * S + row], r = rstd[b * S + row];
            f32x4 wv = *(const f32x4*)(lnw + h * 64 + qc * 4);
            f32x4 bv = *(const f32x4*)(lnb + h * 64 + qc * 4);
            v = (v - m) * r * wv + bv;
        }
        *(f32x4*)&xs[lr][qc * 4] = v;
    }
    __syncthreads();

    // ts[r][lane] = sum_e M[lane][e] * xs[r][e]
    // wave w owns rows lr = w*9 .. w*9+8 (covers 0..35; row 35 is zero-pad)
    {
        int rb = w * 9;
        float acc[9];
        #pragma unroll
        for (int rr = 0; rr < 9; ++rr) acc[rr] = 0.0f;
        #pragma unroll
        for (int eq = 0; eq < 16; ++eq) {
            #pragma unroll
            for (int rr = 0; rr < 9; ++rr) {
                f32x4 xv = *(const f32x4*)&xs[rb + rr][eq * 4];  // uniform broadcast
                acc[rr] += Mreg[eq * 4 + 0] * xv.x + Mreg[eq * 4 + 1] * xv.y +
                           Mreg[eq * 4 + 2] * xv.z + Mreg[eq * 4 + 3] * xv.w;
            }
        }
        #pragma unroll
        for (int rr = 0; rr < 9; ++rr) ts[rb + rr][lane] = acc[rr];
    }
    __syncthreads();

    // score diff, single pass: local rows l = 0..32 (global i = r0 + l)
    //   diff_i = x_i.(t_{i+1}-t_{i-1}) + u.(x_{i+1}-x_{i-1})
    // 4 lanes per row, 16 d-values per lane, shfl-reduce within the 4-lane group.
    {
        int l = t >> 2;       // 0..63; active if l <= 32
        int part = t & 3;
        int i = r0 + l;
        if (l <= 32 && i < S) {
            float diff = 0.0f;
            #pragma unroll
            for (int dq = 0; dq < 4; ++dq) {
                int d0 = part * 16 + dq * 4;
                f32x4 xi = *(const f32x4*)&xs[l + 1][d0];
                f32x4 t2 = *(const f32x4*)&ts[l + 2][d0];
                f32x4 t0 = *(const f32x4*)&ts[l][d0];
                f32x4 x2 = *(const f32x4*)&xs[l + 2][d0];
                f32x4 x0 = *(const f32x4*)&xs[l][d0];
                f32x4 uv = *(const f32x4*)&uvec[d0];  // uniform, L2
                diff += xi.x * (t2.x - t0.x) + uv.x * (x2.x - x0.x);
                diff += xi.y * (t2.y - t0.y) + uv.y * (x2.y - x0.y);
                diff += xi.z * (t2.z - t0.z) + uv.z * (x2.z - x0.z);
                diff += xi.w * (t2.w - t0.w) + uv.w * (x2.w - x0.w);
            }
            diff += __shfl_down(diff, 2);
            diff += __shfl_down(diff, 1);
            if (part == 0) {
                float z = diff * (1.0f / 64.0f);
                float pu, pd;
                if (i == 0)          { pu = 1.0f; pd = 0.0f; }
                else if (i == S - 1) { pu = 0.0f; pd = 1.0f; }
                else {
                    float ez = __expf(-z);
                    pu = 1.0f / (1.0f + ez);
                    pd = 1.0f - pu;
                }
                spu[l] = pu;
                spd[l] = pd;
            }
        }
    }
    __syncthreads();

    // n_up[i] = sqrt(pu[i]*pd[i+1]+1e-4); L[i] = log(prior_blend + 1e-9)
    if (t < 32) {
        int i = r0 + t;
        float L = 0.0f;
        if (i < S - 1) {
            float nr = sqrtf(spu[t] * spd[t + 1] + 1e-4f);
            n_up[bh * S + i] = nr;
            float N = pr_pre + (1.0f - pr_pre) * nr;
            L = logf(N + 1e-9f);
        }
        Lg[bh * S + i] = L;
    }
}

// ---------------- Kernel 3: in-block scan of Lg + big elementwise pass --------------
// grid: 4096 blocks, each handles 8 consecutive rows of one bh; thread = 4 cols.
__global__ __launch_bounds__(256) void k_out(const float* __restrict__ prior,
                                             const float* __restrict__ n_up,
                                             const float* __restrict__ Lg,
                                             float* __restrict__ g_out,
                                             float* __restrict__ nb_out) {
    int t = threadIdx.x;
    int bid = blockIdx.x;          // 0..4095
    int bh = bid >> 7;
    int i0 = (bid & 127) * 8;
    int j0 = t * 4;
    int lane = t & 63, w = t >> 6;

    __shared__ float Csh[1024];
    __shared__ float wtot[4];

    // ---- block-wide exclusive scan of Lg row, pre-scaled by log2(e) ----
    const float LOG2E = 1.4426950408889634f;
    f32x4 q = *(const f32x4*)(Lg + bh * S + j0);
    float e1 = q.x, e2 = q.x + q.y, e3 = e2 + q.z;
    float tot = e3 + q.w;
    float incl = tot;
    #pragma unroll
    for (int off = 1; off < 64; off <<= 1) {
        float v = __shfl_up(incl, off, 64);
        if (lane >= off) incl += v;
    }
    if (lane == 63) wtot[w] = incl;
    __syncthreads();
    float base = incl - tot;          // exclusive within wave
    if (w > 0) base += wtot[0];
    if (w > 1) base += wtot[1];
    if (w > 2) base += wtot[2];
    f32x4 c4;                          // C2[j] = C[j] * log2(e) for this thread's quad
    c4.x = base * LOG2E;
    c4.y = (base + e1) * LOG2E;
    c4.z = (base + e2) * LOG2E;
    c4.w = (base + e3) * LOG2E;
    *(f32x4*)&Csh[j0] = c4;
    __syncthreads();

    f32x4 ciA = *(const f32x4*)&Csh[i0];       // C2[i] for the block's 8 rows (bcast)
    f32x4 ciB = *(const f32x4*)&Csh[i0 + 4];

    #pragma unroll
    for (int r = 0; r < 8; ++r) {
        int i = i0 + r;
        float Ci = (r < 4) ? ciA[r] : ciB[r - 4];
        size_t rowbase = ((size_t)bh * S + i) * S;
        f32x4 p4 = __builtin_nontemporal_load((const f32x4*)(prior + rowbase + j0));
        f32x4 nb, gg;
        // fast path: C monotone non-increasing -> g = exp2(-|C2[j]-C2[i]|)+1e-4, j!=i
        #pragma unroll
        for (int l = 0; l < 4; ++l) {
            nb[l] = fmaf(0.99f, p4[l], 0.01f);
            gg[l] = exp2f(-fabsf(c4[l] - Ci)) + 1e-4f;
        }
        // slow fixup only where [i-1,i+1] intersects [j0,j0+3] (~1 wave per row)
        if (i - 1 <= j0 + 3 && i + 1 >= j0) {
            float nup_i  = (i < S - 1) ? n_up[bh * S + i] : 0.0f;
            float nup_im = (i > 0)     ? n_up[bh * S + i - 1] : 0.0f;
            #pragma unroll
            for (int l = 0; l < 4; ++l) {
                int j = j0 + l;
                if (j == i + 1) nb[l] = p4[l] + (1.0f - p4[l]) * nup_i;
                if (j == i - 1) nb[l] = p4[l] + (1.0f - p4[l]) * nup_im;
                if (j == i)     gg[l] = nb[l];   // diag: g = neibor
            }
        }
        __builtin_nontemporal_store(gg, (f32x4*)(g_out + rowbase + j0));
        __builtin_nontemporal_store(nb, (f32x4*)(nb_out + rowbase + j0));
    }
}

extern "C" void kernel_launch(void* const* d_in, const int* in_sizes, int n_in,
                              void* d_out, int out_size, void* d_ws, size_t ws_size,
                              hipStream_t stream) {
    const float* ctx   = (const float*)d_in[0];
    // d_in[1] = eos_mask (all true) -- unused
    const float* prior = (const float*)d_in[2];
    const float* lnw   = (const float*)d_in[3];
    const float* lnb   = (const float*)d_in[4];
    const float* wk    = (const float*)d_in[5];
    // d_in[6] = bk -- cancels in the score difference
    const float* wq    = (const float*)d_in[7];
    const float* bq    = (const float*)d_in[8];

    float* ws = (float*)d_ws;
    float* mean = ws;                  // 2048
    float* rstd = ws + 2048;           // 2048
    float* Mt   = ws + 4096;           // 4096
    float* uvec = ws + 8192;           // 64 (pad to 256)
    float* n_up = ws + 8448;           // 32*1024
    float* Lg   = ws + 8448 + 32768;   // 32*1024

    float* g_out  = (float*)d_out;
    float* nb_out = (float*)d_out + (size_t)BS * H * S * S;

    k_ln_prep<<<BS * S + 4, 256, 0, stream>>>(ctx, wk, wq, bq, mean, rstd, Mt, uvec);
    k_scores<<<dim3(32, BS * H), 256, 0, stream>>>(ctx, mean, rstd, lnw, lnb, Mt, uvec,
                                                   prior, n_up, Lg);
    k_out<<<BS * H * S / 8, 256, 0, stream>>>(prior, n_up, Lg, g_out, nb_out);
}